// Round 15
// baseline (101677.283 us; speedup 1.0000x reference)
//
#include <hip/hip_runtime.h>
#include <math.h>

#define NB    2048
#define FIN   32
#define HH    512
#define G4    2048           // 4*H
#define BNE   64
#define OUTD  8
#define SEQL  128
#define LOOK  32
#define TOT   (SEQL + LOOK)
#define TB    8              // samples per workgroup
#define NTHR  1024
#define BK    4              // weight rows per staged chunk (32 KB)
#define CHF   (BK * G4)      // floats per chunk (8192)

__device__ __forceinline__ float sigf(float v) { return 1.0f / (1.0f + expf(-v)); }

// async global->LDS DMA, 16 B per lane, bypasses the VGPR/L1-fill return path
__device__ __forceinline__ void dma16(const float* g, float* l) {
  __builtin_amdgcn_global_load_lds(
      (const __attribute__((address_space(1))) unsigned int*)g,
      (__attribute__((address_space(3))) unsigned int*)l, 16, 0, 0);
}

// stage one 32 KB chunk: 16 waves x 2 calls x (64 lanes x 16B)
// LDS dest = wave-uniform base + lane*16B (linear layout required)
#define STAGE_DMA(W, CH, B)                                             \
  { const float* gsrc_ = (W) + (size_t)(CH) * CHF;                      \
    const int wv_ = t >> 6, ln_ = t & 63;                               \
    dma16(gsrc_ + wv_ * 512 + ln_ * 4,                                  \
          &smem[(B) * CHF + wv_ * 512]);                                \
    dma16(gsrc_ + wv_ * 512 + 256 + ln_ * 4,                            \
          &smem[(B) * CHF + wv_ * 512 + 256]); }

// acc[s] (float2) += state_s * w (float2)  — r9 verbatim
#define MAC2(S, HS)                                    \
  {                                                    \
    a[S].x = fmaf(w.x, (HS), a[S].x);                  \
    a[S].y = fmaf(w.y, (HS), a[S].y);                  \
  }
#define MAC2x8()                                       \
  {                                                    \
    MAC2(0, hA.x); MAC2(1, hA.y); MAC2(2, hA.z); MAC2(3, hA.w); \
    MAC2(4, hB.x); MAC2(5, hB.y); MAC2(6, hB.z); MAC2(7, hB.w); \
  }

// compute BK rows of the staged chunk — r9 verbatim
#define CHUNK_COMPUTE(SROW)                                             \
  {                                                                     \
    const float* wb = &smem[cur * CHF];                                 \
    _Pragma("unroll")                                                   \
    for (int kk = 0; kk < BK; kk++) {                                   \
      const float2 w  = *(const float2*)&wb[kk * G4 + 2 * t];           \
      const float*  sr = (SROW);                                        \
      const float4 hA = *(const float4*)&sr[0];                         \
      const float4 hB = *(const float4*)&sr[4];                         \
      MAC2x8();                                                         \
    }                                                                   \
  }

__global__ __launch_bounds__(NTHR)
void fused_rnn(const float* __restrict__ x,
               const float* __restrict__ Wih0, const float* __restrict__ Whh0,
               const float* __restrict__ bih0, const float* __restrict__ bhh0,
               const float* __restrict__ Wih1, const float* __restrict__ Whh1,
               const float* __restrict__ bih1, const float* __restrict__ bhh1,
               const float* __restrict__ We,   const float* __restrict__ be,
               const float* __restrict__ Wd,   const float* __restrict__ bd,
               const float* __restrict__ Wf,   const float* __restrict__ bf,
               float* __restrict__ out)
{
  // states transposed [k][sample]: fixed-k access is a wave-uniform float4 broadcast
  __shared__ float sh0[HH][TB], sc0[HH][TB], sh1[HH][TB], sc1[HH][TB];  // 64 KB
  // OVERLAY (time-disjoint): weight DMA double-buffer during K-loops,
  // gate pre-activations sg[8][2048] after. Both 64 KB.
  __shared__ __attribute__((aligned(16))) float smem[2 * CHF];
  __shared__ float sq[2][BNE][TB];   // trits [ae][j][sample], 4 KB
  __shared__ float sx[FIN][TB];      // staged x_t, transposed, 1 KB
  __shared__ float sout[TB][OUTD];   // last dense output (AR feedback)

#define SG(S, C) smem[(S) * G4 + (C)]

  const int t  = threadIdx.x;          // 0..1023
  const int b0 = blockIdx.x * TB;      // first sample of this WG

  for (int i = t; i < HH * TB; i += NTHR) {
    (&sh0[0][0])[i] = 0.f; (&sc0[0][0])[i] = 0.f;
    (&sh1[0][0])[i] = 0.f; (&sc1[0][0])[i] = 0.f;
  }

  // this thread owns gate cols (2t, 2t+1)
  const float2 bb0 = make_float2(bih0[2*t]   + bhh0[2*t],
                                 bih0[2*t+1] + bhh0[2*t+1]);
  const float2 bb1 = make_float2(bih1[2*t]   + bhh1[2*t],
                                 bih1[2*t+1] + bhh1[2*t+1]);

  const double Athr = 0.5493061443340549;  // atanh(0.5): round(tanh(u)) threshold

  for (int step = 0; step < TOT; ++step) {
    __syncthreads();

    // ---------------- Phase A: encode both AEs (fp64) — r9 verbatim ----------------
    {
      const int ae = t >> 9, s = (t >> 6) & 7, n = t & 63;
      const float* Sh = ae ? &sh1[0][0] : &sh0[0][0];
      const float* Sc = ae ? &sc1[0][0] : &sc0[0][0];
      double a0 = (double)be[n];
      const float* we0 = We + n;
#pragma unroll 4
      for (int k = 0; k < HH; k++)
        a0 = fma((double)Sh[k * TB + s], (double)we0[(size_t)k * BNE], a0);
      const float* we1 = We + (size_t)HH * BNE + n;
#pragma unroll 4
      for (int k = 0; k < HH; k++)
        a0 = fma((double)Sc[k * TB + s], (double)we1[(size_t)k * BNE], a0);
      sq[ae][n][s] = (a0 > Athr) ? 1.f : ((a0 < -Athr) ? -1.f : 0.f);
    }
    __syncthreads();

    // ---------------- Phase B: decode both AEs -> states; stage x_t — r9 verbatim --
    {
      float aq0[TB], aq1[TB];
      const float bdv = bd[t];
#pragma unroll
      for (int s = 0; s < TB; s++) { aq0[s] = bdv; aq1[s] = bdv; }
      const float* wd = Wd + t;          // col t, row stride 1024
#pragma unroll 2
      for (int j = 0; j < BNE; j++) {
        const float w = wd[(size_t)j * (2 * HH)];
        const float4 qA0 = *(const float4*)&sq[0][j][0];
        const float4 qB0 = *(const float4*)&sq[0][j][4];
        const float4 qA1 = *(const float4*)&sq[1][j][0];
        const float4 qB1 = *(const float4*)&sq[1][j][4];
        aq0[0] = fmaf(qA0.x, w, aq0[0]); aq0[1] = fmaf(qA0.y, w, aq0[1]);
        aq0[2] = fmaf(qA0.z, w, aq0[2]); aq0[3] = fmaf(qA0.w, w, aq0[3]);
        aq0[4] = fmaf(qB0.x, w, aq0[4]); aq0[5] = fmaf(qB0.y, w, aq0[5]);
        aq0[6] = fmaf(qB0.z, w, aq0[6]); aq0[7] = fmaf(qB0.w, w, aq0[7]);
        aq1[0] = fmaf(qA1.x, w, aq1[0]); aq1[1] = fmaf(qA1.y, w, aq1[1]);
        aq1[2] = fmaf(qA1.z, w, aq1[2]); aq1[3] = fmaf(qA1.w, w, aq1[3]);
        aq1[4] = fmaf(qB1.x, w, aq1[4]); aq1[5] = fmaf(qB1.y, w, aq1[5]);
        aq1[6] = fmaf(qB1.z, w, aq1[6]); aq1[7] = fmaf(qB1.w, w, aq1[7]);
      }
      if (t < HH) {
#pragma unroll
        for (int s = 0; s < TB; s++) { sh0[t][s] = aq0[s]; sh1[t][s] = aq1[s]; }
      } else {
        const int c = t - HH;
#pragma unroll
        for (int s = 0; s < TB; s++) { sc0[c][s] = aq0[s]; sc1[c][s] = aq1[s]; }
      }
      if (t < FIN * TB) {   // 256 threads stage x_t (with AR feedback)
        int s = t >> 5, f = t & 31;
        float xv;
        if (step >= SEQL && f < OUTD) xv = sout[s][f];
        else xv = x[((size_t)(b0 + s) * TOT + step) * FIN + f];
        sx[f][s] = xv;
      }
      // prefetch Wih0 chunk 0 for phase C — DMA overlaps the coming barrier
      STAGE_DMA(Wih0, 0, 0);
    }
    __syncthreads();

    // ---------------- Phase C: layer-0 matmul (DMA-staged weights) ----------------
    {
      float2 a[TB];
#pragma unroll
      for (int s = 0; s < TB; s++) a[s] = bb0;
      int cur = 0;
      // Wih0: 8 chunks, chain-prefetch into Whh0
      for (int c = 0; c < FIN / BK; c++) {
        if (c < FIN / BK - 1) STAGE_DMA(Wih0, c + 1, cur ^ 1)
        else                  STAGE_DMA(Whh0, 0, cur ^ 1);
        CHUNK_COMPUTE(&sx[BK * c + kk][0]);
        __syncthreads();
        cur ^= 1;
      }
      // Whh0: 128 chunks
      for (int c = 0; c < HH / BK; c++) {
        if (c < HH / BK - 1) STAGE_DMA(Whh0, c + 1, cur ^ 1);
        CHUNK_COMPUTE(&sh0[BK * c + kk][0]);
        __syncthreads();
        cur ^= 1;
      }
#pragma unroll
      for (int s = 0; s < TB; s++) *(float2*)&SG(s, 2 * t) = a[s];
    }
    __syncthreads();
    // layer-0 elementwise: unit h = t&511, 4 samples per thread — r9 verbatim
    {
      const int h  = t & (HH - 1);
      const int sb = (t >> 9) * 4;
#pragma unroll
      for (int s2 = 0; s2 < 4; s2++) {
        const int s = sb + s2;
        const float ig = sigf(SG(s, h));
        const float fg = sigf(SG(s, HH + h));
        const float gt = tanhf(SG(s, 2 * HH + h));
        const float og = sigf(SG(s, 3 * HH + h));
        const float c2 = fmaf(fg, sc0[h][s], ig * gt);
        sc0[h][s] = c2;
        sh0[h][s] = og * tanhf(c2);
      }
    }
    __syncthreads();              // gate reads done
    STAGE_DMA(Wih1, 0, 0);        // prefetch phase-D chunk 0
    __syncthreads();

    // ---------------- Phase D: layer-1 matmul (DMA-staged weights) ----------------
    {
      float2 a[TB];
#pragma unroll
      for (int s = 0; s < TB; s++) a[s] = bb1;
      int cur = 0;
      // Wih1: 128 chunks (input = new h0), chain-prefetch into Whh1
      for (int c = 0; c < HH / BK; c++) {
        if (c < HH / BK - 1) STAGE_DMA(Wih1, c + 1, cur ^ 1)
        else                 STAGE_DMA(Whh1, 0, cur ^ 1);
        CHUNK_COMPUTE(&sh0[BK * c + kk][0]);
        __syncthreads();
        cur ^= 1;
      }
      // Whh1: 128 chunks (recurrent = decoded h1)
      for (int c = 0; c < HH / BK; c++) {
        if (c < HH / BK - 1) STAGE_DMA(Whh1, c + 1, cur ^ 1);
        CHUNK_COMPUTE(&sh1[BK * c + kk][0]);
        __syncthreads();
        cur ^= 1;
      }
#pragma unroll
      for (int s = 0; s < TB; s++) *(float2*)&SG(s, 2 * t) = a[s];
    }
    __syncthreads();
    // layer-1 elementwise — r9 verbatim
    {
      const int h  = t & (HH - 1);
      const int sb = (t >> 9) * 4;
#pragma unroll
      for (int s2 = 0; s2 < 4; s2++) {
        const int s = sb + s2;
        const float ig = sigf(SG(s, h));
        const float fg = sigf(SG(s, HH + h));
        const float gt = tanhf(SG(s, 2 * HH + h));
        const float og = sigf(SG(s, 3 * HH + h));
        const float c2 = fmaf(fg, sc1[h][s], ig * gt);
        sc1[h][s] = c2;
        sh1[h][s] = og * tanhf(c2);
      }
    }

    // ---------------- Phase E: final dense — r9 verbatim ----------------
    if (step >= SEQL - 1) {
      __syncthreads();  // new sh1 visible
      if (t < TB * OUTD) {
        int s = t >> 3, o = t & 7;
        float a = bf[o];
#pragma unroll 4
        for (int k = 0; k < HH; k++) a = fmaf(sh1[k][s], Wf[k * OUTD + o], a);
        sout[s][o] = a;
        int slot = step - (SEQL - 1);                 // 0..32
        out[((size_t)(b0 + s) * (1 + LOOK) + slot) * OUTD + o] = a;
      }
    }
  }
#undef SG
}

extern "C" void kernel_launch(void* const* d_in, const int* in_sizes, int n_in,
                              void* d_out, int out_size, void* d_ws, size_t ws_size,
                              hipStream_t stream) {
  const float* x    = (const float*)d_in[0];
  const float* Wih0 = (const float*)d_in[1];
  const float* Whh0 = (const float*)d_in[2];
  const float* bih0 = (const float*)d_in[3];
  const float* bhh0 = (const float*)d_in[4];
  const float* Wih1 = (const float*)d_in[5];
  const float* Whh1 = (const float*)d_in[6];
  const float* bih1 = (const float*)d_in[7];
  const float* bhh1 = (const float*)d_in[8];
  const float* We   = (const float*)d_in[9];
  const float* be   = (const float*)d_in[10];
  const float* Wd   = (const float*)d_in[11];
  const float* bd   = (const float*)d_in[12];
  const float* Wf   = (const float*)d_in[13];
  const float* bf   = (const float*)d_in[14];

  fused_rnn<<<NB / TB, NTHR, 0, stream>>>(x, Wih0, Whh0, bih0, bhh0,
                                          Wih1, Whh1, bih1, bhh1,
                                          We, be, Wd, bd, Wf, bf,
                                          (float*)d_out);
}

// Round 16
// 79109.058 us; speedup vs baseline: 1.2853x; 1.2853x over previous
//
#include <hip/hip_runtime.h>
#include <math.h>

#define NB    2048
#define FIN   32
#define HH    512
#define G4    2048           // 4*H
#define BNE   64
#define OUTD  8
#define SEQL  128
#define LOOK  32
#define TOT   (SEQL + LOOK)
#define TB    8              // samples per workgroup
#define NTHR  512

__device__ __forceinline__ float sigf(float v) { return 1.0f / (1.0f + expf(-v)); }

// acc[S] (float4 over 4 cols) += w * state_scalar
#define FMA4S(W, HS, S)                                 \
  { acc[S].x = fmaf((W).x, (HS), acc[S].x);             \
    acc[S].y = fmaf((W).y, (HS), acc[S].y);             \
    acc[S].z = fmaf((W).z, (HS), acc[S].z);             \
    acc[S].w = fmaf((W).w, (HS), acc[S].w); }

// one k-row: 4 cols x 8 samples = 32 FMAs
#define FMAROW(W, K, STATE)                             \
  { const float4 hA = *(const float4*)&STATE[K][0];     \
    const float4 hB = *(const float4*)&STATE[K][4];     \
    FMA4S(W, hA.x, 0) FMA4S(W, hA.y, 1)                 \
    FMA4S(W, hA.z, 2) FMA4S(W, hA.w, 3)                 \
    FMA4S(W, hB.x, 4) FMA4S(W, hB.y, 5)                 \
    FMA4S(W, hB.z, 6) FMA4S(W, hB.w, 7) }

// issue 8 weight rows (float4 each) of block KB
#define LOADBLK(DST, WP, KB)                            \
  { _Pragma("unroll")                                   \
    for (int i = 0; i < 8; i++)                         \
      DST[i] = (WP)[((KB) * 8 + i) * (G4 / 4)]; }

// consume block KB (8 rows)
#define FMABLK(SRC, KB, STATE)                          \
  { _Pragma("unroll")                                   \
    for (int i = 0; i < 8; i++) { FMAROW(SRC[i], (KB) * 8 + i, STATE) } }

// K=512: 64 blocks, two-block rolling pipeline (8 float4 loads always in flight)
#define K512_PIPE(WPTR, STATE)                          \
  { const float4* wp = (const float4*)(WPTR) + t;       \
    float4 wa[8], wb[8];                                \
    LOADBLK(wa, wp, 0)                                  \
    _Pragma("unroll 1")                                 \
    for (int kb = 0; kb < 31; kb++) {                   \
      LOADBLK(wb, wp, 2 * kb + 1)                       \
      FMABLK(wa, 2 * kb, STATE)                         \
      LOADBLK(wa, wp, 2 * kb + 2)                       \
      FMABLK(wb, 2 * kb + 1, STATE)                     \
    }                                                   \
    LOADBLK(wb, wp, 63)                                 \
    FMABLK(wa, 62, STATE)                               \
    FMABLK(wb, 63, STATE) }

__global__ __launch_bounds__(NTHR, 2)
void fused_rnn(const float* __restrict__ x,
               const float* __restrict__ Wih0, const float* __restrict__ Whh0,
               const float* __restrict__ bih0, const float* __restrict__ bhh0,
               const float* __restrict__ Wih1, const float* __restrict__ Whh1,
               const float* __restrict__ bih1, const float* __restrict__ bhh1,
               const float* __restrict__ We,   const float* __restrict__ be,
               const float* __restrict__ Wd,   const float* __restrict__ bd,
               const float* __restrict__ Wf,   const float* __restrict__ bf,
               float* __restrict__ out)
{
  // states [unit][sample]: fixed-k access is a wave-uniform b128 broadcast
  __shared__ float sh0[HH][TB], sc0[HH][TB], sh1[HH][TB], sc1[HH][TB];  // 64 KB
  __shared__ float sg[TB][G4];       // gate pre-activations [sample][col], 64 KB
  __shared__ float tq[2][BNE][TB];   // trits as float, 4 KB
  __shared__ float sx[FIN][TB];      // staged x_t, 1 KB
  __shared__ float sout[TB][OUTD];   // dense output (AR feedback)

  const int t  = threadIdx.x;          // 0..511
  const int b0 = blockIdx.x * TB;

  for (int i = t; i < HH * TB; i += NTHR) {
    (&sh0[0][0])[i] = 0.f; (&sc0[0][0])[i] = 0.f;
    (&sh1[0][0])[i] = 0.f; (&sc1[0][0])[i] = 0.f;
  }

  // matmul mapping: thread owns 4 contiguous gate cols [4t, 4t+4), all 8 samples
  float4 bg0, bg1;
  { const float4 a = *(const float4*)&bih0[4 * t];
    const float4 b = *(const float4*)&bhh0[4 * t];
    bg0 = make_float4(a.x + b.x, a.y + b.y, a.z + b.z, a.w + b.w); }
  { const float4 a = *(const float4*)&bih1[4 * t];
    const float4 b = *(const float4*)&bhh1[4 * t];
    bg1 = make_float4(a.x + b.x, a.y + b.y, a.z + b.z, a.w + b.w); }

  // encoder mapping (r2 verbatim): (ae, n, sample-pair)
  const int ae = t >> 8, n = t & 63, sp = (t >> 6) & 3;

  const double Athr = 0.5493061443340549;  // atanh(0.5)

  for (int step = 0; step < TOT; ++step) {
    __syncthreads();

    // ================= A: AE encoders (fp64, 2 samples/thread) ========
    {
      const float* Sh = ae ? &sh1[0][0] : &sh0[0][0];
      const float* Sc = ae ? &sc1[0][0] : &sc0[0][0];
      double a0 = (double)be[n], a1 = a0;
      const float* weh = We + n;
#pragma unroll 4
      for (int k = 0; k < HH; k++) {
        const float2 zz = *(const float2*)&Sh[k * TB + 2 * sp];
        const double wv = (double)weh[(size_t)k * BNE];
        a0 = fma((double)zz.x, wv, a0);
        a1 = fma((double)zz.y, wv, a1);
      }
      const float* wec = We + (size_t)HH * BNE + n;
#pragma unroll 4
      for (int k = 0; k < HH; k++) {
        const float2 zz = *(const float2*)&Sc[k * TB + 2 * sp];
        const double wv = (double)wec[(size_t)k * BNE];
        a0 = fma((double)zz.x, wv, a0);
        a1 = fma((double)zz.y, wv, a1);
      }
      tq[ae][n][2 * sp]     = (a0 > Athr) ? 1.f : ((a0 < -Athr) ? -1.f : 0.f);
      tq[ae][n][2 * sp + 1] = (a1 > Athr) ? 1.f : ((a1 < -Athr) ? -1.f : 0.f);
    }
    __syncthreads();

    // ================= B: AE decode (col t h-part + col 512+t c-part) ==
    {
      float aq0[TB], aq1[TB], ac0[TB], ac1[TB];
      const float bdh = bd[t], bdc = bd[HH + t];
#pragma unroll
      for (int s = 0; s < TB; s++) { aq0[s] = bdh; ac0[s] = bdc; aq1[s] = bdh; ac1[s] = bdc; }
      const float* wd0 = Wd + t;            // h-part col t
      const float* wd1 = Wd + HH + t;       // c-part col 512+t
#pragma unroll 2
      for (int j = 0; j < BNE; j++) {
        const float w0 = wd0[(size_t)j * (2 * HH)];
        const float w1 = wd1[(size_t)j * (2 * HH)];
        const float4 qA0 = *(const float4*)&tq[0][j][0];
        const float4 qB0 = *(const float4*)&tq[0][j][4];
        const float4 qA1 = *(const float4*)&tq[1][j][0];
        const float4 qB1 = *(const float4*)&tq[1][j][4];
        aq0[0] = fmaf(qA0.x, w0, aq0[0]); ac0[0] = fmaf(qA0.x, w1, ac0[0]);
        aq0[1] = fmaf(qA0.y, w0, aq0[1]); ac0[1] = fmaf(qA0.y, w1, ac0[1]);
        aq0[2] = fmaf(qA0.z, w0, aq0[2]); ac0[2] = fmaf(qA0.z, w1, ac0[2]);
        aq0[3] = fmaf(qA0.w, w0, aq0[3]); ac0[3] = fmaf(qA0.w, w1, ac0[3]);
        aq0[4] = fmaf(qB0.x, w0, aq0[4]); ac0[4] = fmaf(qB0.x, w1, ac0[4]);
        aq0[5] = fmaf(qB0.y, w0, aq0[5]); ac0[5] = fmaf(qB0.y, w1, ac0[5]);
        aq0[6] = fmaf(qB0.z, w0, aq0[6]); ac0[6] = fmaf(qB0.z, w1, ac0[6]);
        aq0[7] = fmaf(qB0.w, w0, aq0[7]); ac0[7] = fmaf(qB0.w, w1, ac0[7]);
        aq1[0] = fmaf(qA1.x, w0, aq1[0]); ac1[0] = fmaf(qA1.x, w1, ac1[0]);
        aq1[1] = fmaf(qA1.y, w0, aq1[1]); ac1[1] = fmaf(qA1.y, w1, ac1[1]);
        aq1[2] = fmaf(qA1.z, w0, aq1[2]); ac1[2] = fmaf(qA1.z, w1, ac1[2]);
        aq1[3] = fmaf(qA1.w, w0, aq1[3]); ac1[3] = fmaf(qA1.w, w1, ac1[3]);
        aq1[4] = fmaf(qB1.x, w0, aq1[4]); ac1[4] = fmaf(qB1.x, w1, ac1[4]);
        aq1[5] = fmaf(qB1.y, w0, aq1[5]); ac1[5] = fmaf(qB1.y, w1, ac1[5]);
        aq1[6] = fmaf(qB1.z, w0, aq1[6]); ac1[6] = fmaf(qB1.z, w1, ac1[6]);
        aq1[7] = fmaf(qB1.w, w0, aq1[7]); ac1[7] = fmaf(qB1.w, w1, ac1[7]);
      }
#pragma unroll
      for (int s = 0; s < TB; s++) {
        sh0[t][s] = aq0[s]; sc0[t][s] = ac0[s];
        sh1[t][s] = aq1[s]; sc1[t][s] = ac1[s];
      }
      if (t < FIN * TB) {        // stage x_t (with AR feedback)
        int s = t >> 5, f = t & 31;
        float xv;
        if (step >= SEQL && f < OUTD) xv = sout[s][f];
        else xv = x[((size_t)(b0 + s) * TOT + step) * FIN + f];
        sx[f][s] = xv;
      }
    }
    __syncthreads();

    // ================= C: layer-0 matmul (pipelined float4 weights) ================
    {
      float4 acc[TB];
#pragma unroll
      for (int s = 0; s < TB; s++) acc[s] = bg0;
      { // x part, K=32: 4 blocks
        const float4* wp = (const float4*)Wih0 + t;
        float4 wa[8], wb[8];
        LOADBLK(wa, wp, 0)
        LOADBLK(wb, wp, 1)
        FMABLK(wa, 0, sx)
        LOADBLK(wa, wp, 2)
        FMABLK(wb, 1, sx)
        LOADBLK(wb, wp, 3)
        FMABLK(wa, 2, sx)
        FMABLK(wb, 3, sx)
      }
      K512_PIPE(Whh0, sh0)
#pragma unroll
      for (int s = 0; s < TB; s++) *(float4*)&sg[s][4 * t] = acc[s];
    }
    __syncthreads();
    // layer-0 elementwise: thread = unit t, all 8 samples
    {
#pragma unroll 2
      for (int s = 0; s < TB; s++) {
        const float ig = sigf(sg[s][t]);
        const float fg = sigf(sg[s][HH + t]);
        const float gt = tanhf(sg[s][2 * HH + t]);
        const float og = sigf(sg[s][3 * HH + t]);
        const float c2 = fmaf(fg, sc0[t][s], ig * gt);
        sc0[t][s] = c2;
        sh0[t][s] = og * tanhf(c2);
      }
    }
    __syncthreads();

    // ================= D: layer-1 matmul =================
    {
      float4 acc[TB];
#pragma unroll
      for (int s = 0; s < TB; s++) acc[s] = bg1;
      K512_PIPE(Wih1, sh0)    // input = new h0
      K512_PIPE(Whh1, sh1)    // recurrent = decoded h1
#pragma unroll
      for (int s = 0; s < TB; s++) *(float4*)&sg[s][4 * t] = acc[s];
    }
    __syncthreads();
    // layer-1 elementwise
    {
#pragma unroll 2
      for (int s = 0; s < TB; s++) {
        const float ig = sigf(sg[s][t]);
        const float fg = sigf(sg[s][HH + t]);
        const float gt = tanhf(sg[s][2 * HH + t]);
        const float og = sigf(sg[s][3 * HH + t]);
        const float c2 = fmaf(fg, sc1[t][s], ig * gt);
        sc1[t][s] = c2;
        sh1[t][s] = og * tanhf(c2);
      }
    }

    // ================= E: final dense =================
    if (step >= SEQL - 1) {
      __syncthreads();  // new sh1 visible
      if (t < TB * OUTD) {
        int s = t >> 3, o = t & 7;
        float a = bf[o];
#pragma unroll 4
        for (int k = 0; k < HH; k++) a = fmaf(sh1[k][s], Wf[k * OUTD + o], a);
        sout[s][o] = a;
        int slot = step - (SEQL - 1);
        out[((size_t)(b0 + s) * (1 + LOOK) + slot) * OUTD + o] = a;
      }
    }
  }
}

extern "C" void kernel_launch(void* const* d_in, const int* in_sizes, int n_in,
                              void* d_out, int out_size, void* d_ws, size_t ws_size,
                              hipStream_t stream) {
  const float* x    = (const float*)d_in[0];
  const float* Wih0 = (const float*)d_in[1];
  const float* Whh0 = (const float*)d_in[2];
  const float* bih0 = (const float*)d_in[3];
  const float* bhh0 = (const float*)d_in[4];
  const float* Wih1 = (const float*)d_in[5];
  const float* Whh1 = (const float*)d_in[6];
  const float* bih1 = (const float*)d_in[7];
  const float* bhh1 = (const float*)d_in[8];
  const float* We   = (const float*)d_in[9];
  const float* be   = (const float*)d_in[10];
  const float* Wd   = (const float*)d_in[11];
  const float* bd   = (const float*)d_in[12];
  const float* Wf   = (const float*)d_in[13];
  const float* bf   = (const float*)d_in[14];

  fused_rnn<<<NB / TB, NTHR, 0, stream>>>(x, Wih0, Whh0, bih0, bhh0,
                                          Wih1, Whh1, bih1, bhh1,
                                          We, be, Wd, bd, Wf, bf,
                                          (float*)d_out);
}